// Round 1
// baseline (283.261 us; speedup 1.0000x reference)
//
#include <hip/hip_runtime.h>
#include <stdint.h>

typedef _Float16 f16;
typedef _Float16 f16x4 __attribute__((ext_vector_type(4)));
typedef _Float16 f16x8 __attribute__((ext_vector_type(8)));
typedef float f32x4 __attribute__((ext_vector_type(4)));

#define NHEADS 8
#define DH 64
#define BATCH 2
#define SEQ 4096
#define CDIM 512
#define MTOT (BATCH * SEQ)

__device__ __forceinline__ void gload_lds16(const void* g, void* l) {
  __builtin_amdgcn_global_load_lds(
      (const __attribute__((address_space(1))) uint32_t*)g,
      (__attribute__((address_space(3))) uint32_t*)l, 16, 0, 0);
}

__global__ void cvt_f32_f16(const float* __restrict__ in, f16* __restrict__ outp, int n) {
  int i = (blockIdx.x * 256 + threadIdx.x) * 4;
  if (i < n) {
    float4 v = *(const float4*)(in + i);
    f16x4 o = {(f16)v.x, (f16)v.y, (f16)v.z, (f16)v.w};
    *(f16x4*)(outp + i) = o;
  }
}

__global__ void cvt_transpose(const float* __restrict__ src, f16* __restrict__ dst, int Kd, int Nd) {
  int i = blockIdx.x * 256 + threadIdx.x;
  if (i < Kd * Nd) {
    int k = i / Nd, n = i - k * Nd;
    dst[(size_t)n * Kd + k] = (f16)src[i];
  }
}

// C = A[M,512] * Bt[N,512]^T ; tiles 128x128, BK=64, 4 waves (2x2), 16x16x32 MFMA
// MODE 0: scatter into Q/K [bh][n][d] and V-transposed [bh][d][n] (f16, +bias)
// MODE 1: dense f32 out [M,512] (+bias)
template <int MODE>
__global__ __launch_bounds__(256) void gemm_f16(
    const f16* __restrict__ A, const f16* __restrict__ Bt,
    const float* __restrict__ bias, int Ncols,
    f16* __restrict__ Qo, f16* __restrict__ Ko, f16* __restrict__ Vo,
    float* __restrict__ Fo) {
  const int K = CDIM;
  const int nTN = Ncols >> 7;
  const int bm = blockIdx.x / nTN, bn = blockIdx.x % nTN;
  const int M0 = bm << 7, N0 = bn << 7;
  __shared__ __align__(16) char ldsA[128 * 64 * 2];
  __shared__ __align__(16) char ldsB[128 * 64 * 2];
  const int t = threadIdx.x;
  const int w = t >> 6, lane = t & 63;
  const int wr = w >> 1, wc = w & 1;
  const int lm = lane & 15, lk = lane >> 4;
  f32x4 acc[4][4] = {};

  const int srow = t >> 3;  // flat=(q*256+t) -> row=q*32+srow
  const int sj = t & 7;

  for (int k0 = 0; k0 < K; k0 += 64) {
    __syncthreads();
#pragma unroll
    for (int q = 0; q < 4; ++q) {
      int row = (q << 5) + srow;
      int col = (sj ^ (row & 7)) << 3;  // pre-swizzled global source (linear LDS dest)
      gload_lds16(A + (size_t)(M0 + row) * K + k0 + col,
                  ldsA + ((q << 8) + (w << 6)) * 16);
      gload_lds16(Bt + (size_t)(N0 + row) * K + k0 + col,
                  ldsB + ((q << 8) + (w << 6)) * 16);
    }
    asm volatile("s_waitcnt vmcnt(0)" ::: "memory");
    __syncthreads();
#pragma unroll
    for (int h = 0; h < 2; ++h) {
      f16x8 af[4], bf[4];
#pragma unroll
      for (int mi = 0; mi < 4; ++mi) {
        int row = (wr << 6) + (mi << 4) + lm;
        int slot = ((h << 2) + lk) ^ (row & 7);
        af[mi] = *(const f16x8*)(ldsA + row * 128 + slot * 16);
      }
#pragma unroll
      for (int ni = 0; ni < 4; ++ni) {
        int row = (wc << 6) + (ni << 4) + lm;
        int slot = ((h << 2) + lk) ^ (row & 7);
        bf[ni] = *(const f16x8*)(ldsB + row * 128 + slot * 16);
      }
#pragma unroll
      for (int mi = 0; mi < 4; ++mi)
#pragma unroll
        for (int ni = 0; ni < 4; ++ni)
          acc[mi][ni] = __builtin_amdgcn_mfma_f32_16x16x32_f16(af[mi], bf[ni], acc[mi][ni], 0, 0, 0);
    }
  }

  const int cbase = N0 + (wc << 6);
  if (MODE == 0) {
    const int tsec = cbase >> 9;          // 0=Q 1=K 2=V (uniform per block: 128 | 512)
    const int hh = (cbase & 511) >> 6;    // head (uniform per wave-column)
#pragma unroll
    for (int mi = 0; mi < 4; ++mi)
#pragma unroll
      for (int ni = 0; ni < 4; ++ni) {
        int c = cbase + (ni << 4) + lm;
        int d = c & 63;
        float bv = bias[c];
#pragma unroll
        for (int r = 0; r < 4; ++r) {
          int m = M0 + (wr << 6) + (mi << 4) + (lk << 2) + r;
          float v = acc[mi][ni][r] + bv;
          int bb = m >> 12, tok = m & 4095;
          size_t bh = (size_t)bb * NHEADS + hh;
          if (tsec == 0)      Qo[(bh * SEQ + tok) * DH + d] = (f16)v;
          else if (tsec == 1) Ko[(bh * SEQ + tok) * DH + d] = (f16)v;
          else                Vo[(bh * DH + d) * SEQ + tok] = (f16)v;
        }
      }
  } else {
#pragma unroll
    for (int mi = 0; mi < 4; ++mi)
#pragma unroll
      for (int ni = 0; ni < 4; ++ni) {
        int c = cbase + (ni << 4) + lm;
        float bv = bias[c];
#pragma unroll
        for (int r = 0; r < 4; ++r) {
          int m = M0 + (wr << 6) + (mi << 4) + (lk << 2) + r;
          Fo[(size_t)m * CDIM + c] = acc[mi][ni][r] + bv;
        }
      }
  }
}

// Flash attention: grid = 16 (b*h) x 64 q-tiles; block = 4 waves, wave owns 16 q-rows.
// K tile [64 kv][64 d] and V^T tile [64 d][64 kv] staged via global_load_lds, XOR-swizzled.
__global__ __launch_bounds__(256) void attn_f16(
    const f16* __restrict__ Qw, const f16* __restrict__ Kw,
    const f16* __restrict__ Vw, f16* __restrict__ Ao) {
  const int bh = blockIdx.x >> 6;
  const int qt = blockIdx.x & 63;
  const int t = threadIdx.x, w = t >> 6, lane = t & 63;
  const int lm = lane & 15, lk = lane >> 4;
  __shared__ __align__(16) char ldsK[64 * 128];
  __shared__ __align__(16) char ldsV[64 * 128];
  __shared__ __align__(16) char ldsP[4 * 16 * 128];
  const float scale = 0.125f;  // 1/sqrt(64)
  const int q0 = (qt << 6) + (w << 4);
  const f16* Qb = Qw + ((size_t)bh * SEQ + q0) * DH;
  f16x8 aq[2];
#pragma unroll
  for (int h = 0; h < 2; ++h)
    aq[h] = *(const f16x8*)(Qb + lm * DH + h * 32 + lk * 8);
  f32x4 o[4] = {};
  float mrow[4], lrow[4];
#pragma unroll
  for (int i = 0; i < 4; ++i) { mrow[i] = -1e30f; lrow[i] = 0.f; }
  const f16* Kb = Kw + (size_t)bh * SEQ * DH;
  const f16* Vb = Vw + (size_t)bh * DH * SEQ;
  const int srow = t >> 3, sj = t & 7;
  char* Pb = ldsP + (w << 11);

  for (int tt = 0; tt < 64; ++tt) {
    const int kv0 = tt << 6;
    __syncthreads();
#pragma unroll
    for (int q = 0; q < 2; ++q) {
      int row = (q << 5) + srow;
      int col = (sj ^ (row & 7)) << 3;
      gload_lds16(Kb + (size_t)(kv0 + row) * DH + col, ldsK + ((q << 8) + (w << 6)) * 16);
      gload_lds16(Vb + (size_t)row * SEQ + kv0 + col, ldsV + ((q << 8) + (w << 6)) * 16);
    }
    asm volatile("s_waitcnt vmcnt(0)" ::: "memory");
    __syncthreads();

    // S = Q K^T (per wave: 16 q-rows x 64 kv)
    f32x4 s[4] = {};
#pragma unroll
    for (int h = 0; h < 2; ++h)
#pragma unroll
      for (int nc = 0; nc < 4; ++nc) {
        int row = (nc << 4) + lm;
        int slot = ((h << 2) + lk) ^ (row & 7);
        f16x8 bk = *(const f16x8*)(ldsK + row * 128 + slot * 16);
        s[nc] = __builtin_amdgcn_mfma_f32_16x16x32_f16(aq[h], bk, s[nc], 0, 0, 0);
      }

    // online softmax; lane holds rows (lk*4+i), cols (nc*16+lm)
    float pmax[4];
#pragma unroll
    for (int i = 0; i < 4; ++i)
      pmax[i] = fmaxf(fmaxf(s[0][i], s[1][i]), fmaxf(s[2][i], s[3][i])) * scale;
#pragma unroll
    for (int off = 1; off < 16; off <<= 1)
#pragma unroll
      for (int i = 0; i < 4; ++i)
        pmax[i] = fmaxf(pmax[i], __shfl_xor(pmax[i], off, 64));
    float fsc[4], mnew[4];
#pragma unroll
    for (int i = 0; i < 4; ++i) {
      mnew[i] = fmaxf(mrow[i], pmax[i]);
      fsc[i] = __expf(mrow[i] - mnew[i]);
      mrow[i] = mnew[i];
    }
    float p[4][4], psum[4] = {0.f, 0.f, 0.f, 0.f};
#pragma unroll
    for (int nc = 0; nc < 4; ++nc)
#pragma unroll
      for (int i = 0; i < 4; ++i) {
        float e = __expf(s[nc][i] * scale - mnew[i]);
        p[nc][i] = e;
        psum[i] += e;
      }
#pragma unroll
    for (int off = 1; off < 16; off <<= 1)
#pragma unroll
      for (int i = 0; i < 4; ++i)
        psum[i] += __shfl_xor(psum[i], off, 64);
#pragma unroll
    for (int i = 0; i < 4; ++i) lrow[i] = lrow[i] * fsc[i] + psum[i];
#pragma unroll
    for (int dc = 0; dc < 4; ++dc)
#pragma unroll
      for (int i = 0; i < 4; ++i) o[dc][i] *= fsc[i];

    // P -> per-wave LDS (swizzled), then re-read in A-fragment layout
#pragma unroll
    for (int nc = 0; nc < 4; ++nc)
#pragma unroll
      for (int i = 0; i < 4; ++i) {
        int r = (lk << 2) + i;
        int c = (nc << 4) + lm;
        int slot = (c >> 3) ^ (r & 7);
        *(f16*)(Pb + r * 128 + slot * 16 + ((c & 7) << 1)) = (f16)p[nc][i];
      }
    asm volatile("s_waitcnt lgkmcnt(0)" ::: "memory");
    __builtin_amdgcn_sched_barrier(0);

    // O += P V
#pragma unroll
    for (int h = 0; h < 2; ++h) {
      int slotp = ((h << 2) + lk) ^ (lm & 7);
      f16x8 ap = *(const f16x8*)(Pb + lm * 128 + slotp * 16);
#pragma unroll
      for (int dc = 0; dc < 4; ++dc) {
        int row = (dc << 4) + lm;
        int slot = ((h << 2) + lk) ^ (row & 7);
        f16x8 bv = *(const f16x8*)(ldsV + row * 128 + slot * 16);
        o[dc] = __builtin_amdgcn_mfma_f32_16x16x32_f16(ap, bv, o[dc], 0, 0, 0);
      }
    }
  }

  const int b_ = bh >> 3, h_ = bh & 7;
#pragma unroll
  for (int dc = 0; dc < 4; ++dc)
#pragma unroll
    for (int i = 0; i < 4; ++i) {
      int tok = q0 + (lk << 2) + i;
      float v = o[dc][i] / lrow[i];
      Ao[((size_t)b_ * SEQ + tok) * CDIM + (h_ << 6) + (dc << 4) + lm] = (f16)v;
    }
}

extern "C" void kernel_launch(void* const* d_in, const int* in_sizes, int n_in,
                              void* d_out, int out_size, void* d_ws, size_t ws_size,
                              hipStream_t stream) {
  const float* x = (const float*)d_in[0];
  const float* Wqkv = (const float*)d_in[1];
  const float* bqkv = (const float*)d_in[2];
  const float* Wproj = (const float*)d_in[3];
  const float* bproj = (const float*)d_in[4];
  float* out = (float*)d_out;
  char* ws = (char*)d_ws;

  const size_t SZ_X = (size_t)MTOT * CDIM * 2;  // 8 MiB
  f16* xb = (f16*)(ws);
  f16* attno = xb;  // alias: xb is dead after QKV GEMM
  f16* wqkvT = (f16*)(ws + SZ_X);
  f16* wprojT = (f16*)(ws + SZ_X + (size_t)1536 * 512 * 2);
  f16* Qwv = (f16*)(ws + SZ_X + (size_t)1536 * 512 * 2 + (size_t)512 * 512 * 2);
  f16* Kwv = (f16*)((char*)Qwv + SZ_X);
  f16* Vwv = (f16*)((char*)Kwv + SZ_X);

  cvt_f32_f16<<<(MTOT * CDIM / 4 + 255) / 256, 256, 0, stream>>>(x, xb, MTOT * CDIM);
  cvt_transpose<<<(512 * 1536 + 255) / 256, 256, 0, stream>>>(Wqkv, wqkvT, 512, 1536);
  cvt_transpose<<<(512 * 512 + 255) / 256, 256, 0, stream>>>(Wproj, wprojT, 512, 512);
  gemm_f16<0><<<64 * 12, 256, 0, stream>>>(xb, wqkvT, bqkv, 1536, Qwv, Kwv, Vwv, nullptr);
  attn_f16<<<16 * 64, 256, 0, stream>>>(Qwv, Kwv, Vwv, attno);
  gemm_f16<1><<<64 * 4, 256, 0, stream>>>(attno, wprojT, bproj, 512, nullptr, nullptr, nullptr, out);
}

// Round 3
// 186.508 us; speedup vs baseline: 1.5188x; 1.5188x over previous
//
#include <hip/hip_runtime.h>
#include <stdint.h>

typedef _Float16 f16;
typedef _Float16 f16x4 __attribute__((ext_vector_type(4)));
typedef _Float16 f16x8 __attribute__((ext_vector_type(8)));
typedef float f32x4 __attribute__((ext_vector_type(4)));
typedef float f32x16 __attribute__((ext_vector_type(16)));
typedef uint32_t u32;
typedef u32 u32x2 __attribute__((ext_vector_type(2)));
typedef u32 u32x4 __attribute__((ext_vector_type(4)));

#define NHEADS 8
#define DH 64
#define BATCH 2
#define SEQ 4096
#define CDIM 512
#define MTOT (BATCH * SEQ)
// softmax scale (1/sqrt(64)) * log2(e), folded into Q at the QKV epilogue
#define QSCALE 0.18033688011112042f

__device__ __forceinline__ void gload_lds16(const void* g, void* l) {
  __builtin_amdgcn_global_load_lds(
      (const __attribute__((address_space(1))) uint32_t*)g,
      (__attribute__((address_space(3))) uint32_t*)l, 16, 0, 0);
}

__device__ __forceinline__ u32 pk2(float a, float b) {
  auto h = __builtin_amdgcn_cvt_pkrtz(a, b);  // __fp16 ext_vector(2)
  return __builtin_bit_cast(u32, h);
}

__device__ __forceinline__ void pl32swap(u32& a, u32& b) {
  asm volatile("v_permlane32_swap_b32 %0, %1" : "+v"(a), "+v"(b));
}

__global__ void cvt_f32_f16(const float* __restrict__ in, f16* __restrict__ outp, int n) {
  int i = (blockIdx.x * 256 + threadIdx.x) * 4;
  if (i < n) {
    float4 v = *(const float4*)(in + i);
    f16x4 o = {(f16)v.x, (f16)v.y, (f16)v.z, (f16)v.w};
    *(f16x4*)(outp + i) = o;
  }
}

__global__ void cvt_transpose(const float* __restrict__ src, f16* __restrict__ dst, int Kd, int Nd) {
  int i = blockIdx.x * 256 + threadIdx.x;
  if (i < Kd * Nd) {
    int k = i / Nd, n = i - k * Nd;
    dst[(size_t)n * Kd + k] = (f16)src[i];
  }
}

// C = A[M,512] * Bt[N,512]^T ; tiles 128x128, BK=64, 4 waves (2x2), 16x16x32 MFMA
template <int MODE>
__global__ __launch_bounds__(256) void gemm_f16(
    const f16* __restrict__ A, const f16* __restrict__ Bt,
    const float* __restrict__ bias, int Ncols,
    f16* __restrict__ Qo, f16* __restrict__ Ko, f16* __restrict__ Vo,
    float* __restrict__ Fo) {
  const int K = CDIM;
  const int nTN = Ncols >> 7;
  const int bm = blockIdx.x / nTN, bn = blockIdx.x % nTN;
  const int M0 = bm << 7, N0 = bn << 7;
  __shared__ __align__(16) char ldsA[128 * 64 * 2];
  __shared__ __align__(16) char ldsB[128 * 64 * 2];
  const int t = threadIdx.x;
  const int w = t >> 6, lane = t & 63;
  const int wr = w >> 1, wc = w & 1;
  const int lm = lane & 15, lk = lane >> 4;
  f32x4 acc[4][4] = {};

  const int srow = t >> 3;
  const int sj = t & 7;

  for (int k0 = 0; k0 < K; k0 += 64) {
    __syncthreads();
#pragma unroll
    for (int q = 0; q < 4; ++q) {
      int row = (q << 5) + srow;
      int col = (sj ^ (row & 7)) << 3;
      gload_lds16(A + (size_t)(M0 + row) * K + k0 + col,
                  ldsA + ((q << 8) + (w << 6)) * 16);
      gload_lds16(Bt + (size_t)(N0 + row) * K + k0 + col,
                  ldsB + ((q << 8) + (w << 6)) * 16);
    }
    asm volatile("s_waitcnt vmcnt(0)" ::: "memory");
    __syncthreads();
#pragma unroll
    for (int h = 0; h < 2; ++h) {
      f16x8 af[4], bf[4];
#pragma unroll
      for (int mi = 0; mi < 4; ++mi) {
        int row = (wr << 6) + (mi << 4) + lm;
        int slot = ((h << 2) + lk) ^ (row & 7);
        af[mi] = *(const f16x8*)(ldsA + row * 128 + slot * 16);
      }
#pragma unroll
      for (int ni = 0; ni < 4; ++ni) {
        int row = (wc << 6) + (ni << 4) + lm;
        int slot = ((h << 2) + lk) ^ (row & 7);
        bf[ni] = *(const f16x8*)(ldsB + row * 128 + slot * 16);
      }
#pragma unroll
      for (int mi = 0; mi < 4; ++mi)
#pragma unroll
        for (int ni = 0; ni < 4; ++ni)
          acc[mi][ni] = __builtin_amdgcn_mfma_f32_16x16x32_f16(af[mi], bf[ni], acc[mi][ni], 0, 0, 0);
    }
  }

  const int cbase = N0 + (wc << 6);
  if (MODE == 0) {
    const int tsec = cbase >> 9;
    const int hh = (cbase & 511) >> 6;
#pragma unroll
    for (int mi = 0; mi < 4; ++mi)
#pragma unroll
      for (int ni = 0; ni < 4; ++ni) {
        int c = cbase + (ni << 4) + lm;
        int d = c & 63;
        float bv = bias[c];
#pragma unroll
        for (int r = 0; r < 4; ++r) {
          int m = M0 + (wr << 6) + (mi << 4) + (lk << 2) + r;
          float v = acc[mi][ni][r] + bv;
          int bb = m >> 12, tok = m & 4095;
          size_t bh = (size_t)bb * NHEADS + hh;
          if (tsec == 0)      Qo[(bh * SEQ + tok) * DH + d] = (f16)(v * QSCALE);
          else if (tsec == 1) Ko[(bh * SEQ + tok) * DH + d] = (f16)v;
          else                Vo[(bh * DH + d) * SEQ + tok] = (f16)v;
        }
      }
  } else {
#pragma unroll
    for (int mi = 0; mi < 4; ++mi)
#pragma unroll
      for (int ni = 0; ni < 4; ++ni) {
        int c = cbase + (ni << 4) + lm;
        float bv = bias[c];
#pragma unroll
        for (int r = 0; r < 4; ++r) {
          int m = M0 + (wr << 6) + (mi << 4) + (lk << 2) + r;
          Fo[(size_t)m * CDIM + c] = acc[mi][ni][r] + bv;
        }
      }
  }
}

// Flash attention, swapped-QK^T 32x32 structure.
// grid = 16 bh x 32 q-tiles(128); block = 4 waves; wave owns 32 q-rows.
// S^T = mfma(K, Q) so each lane holds a full 32-element P-row slice for one q.
// PV computed as O^T = mfma(V^T, P^T); P repacked in-register via cvt_pkrtz +
// v_permlane32_swap. K/V tiles (64kv) double-buffered via global_load_lds.
__global__ __launch_bounds__(256) void attn_f16(
    const f16* __restrict__ Qw, const f16* __restrict__ Kw,
    const f16* __restrict__ Vw, f16* __restrict__ Ao) {
  const int bh = blockIdx.x >> 5;
  const int qt = blockIdx.x & 31;
  const int t = threadIdx.x, lane = t & 63;
  const int l31 = lane & 31, hi = lane >> 5;
  const int w = t >> 6;
  __shared__ __align__(16) char ldsK[2][64 * 128];
  __shared__ __align__(16) char ldsV[2][64 * 128];
  const int q0 = (qt << 7) + (w << 5);
  const int myq = q0 + l31;
  const f16* Qb = Qw + ((size_t)bh * SEQ + myq) * DH;
  f16x8 qf[4];
#pragma unroll
  for (int cd = 0; cd < 4; ++cd)
    qf[cd] = *(const f16x8*)(Qb + cd * 16 + hi * 8);
  f32x16 o0 = {}, o1 = {};
  float m = -1e30f, l = 0.f;
  const f16* Kb = Kw + (size_t)bh * SEQ * DH;
  const f16* Vb = Vw + (size_t)bh * DH * SEQ;
  const int srow = t >> 3, sj = t & 7;

#define STAGE(buf, kv0_)                                                      \
  {                                                                           \
    _Pragma("unroll") for (int q2 = 0; q2 < 2; ++q2) {                        \
      const int row = (q2 << 5) + srow;                                       \
      const int col = (sj ^ (row & 7)) << 3;                                  \
      gload_lds16(Kb + (size_t)((kv0_) + row) * DH + col,                     \
                  ldsK[buf] + (q2 << 12) + srow * 128 + sj * 16);             \
      gload_lds16(Vb + (size_t)row * SEQ + (kv0_) + col,                      \
                  ldsV[buf] + (q2 << 12) + srow * 128 + sj * 16);             \
    }                                                                         \
  }

  STAGE(0, 0);
  __syncthreads();

#pragma unroll 1
  for (int tt = 0; tt < 64; ++tt) {
    const int cur = tt & 1;
    const char* Kc = ldsK[cur];
    const char* Vc = ldsV[cur];
    if (tt < 63) STAGE(cur ^ 1, (tt + 1) << 6);

    // S^T[kv][q]: 2 kv-halves x 4 d-chunks
    f32x16 s0 = {}, s1 = {};
#pragma unroll
    for (int cd = 0; cd < 4; ++cd) {
      const int sl = (((cd << 1) | hi) ^ (l31 & 7)) << 4;
      f16x8 k0 = *(const f16x8*)(Kc + l31 * 128 + sl);
      f16x8 k1 = *(const f16x8*)(Kc + (32 + l31) * 128 + sl);
      s0 = __builtin_amdgcn_mfma_f32_32x32x16_f16(k0, qf[cd], s0, 0, 0, 0);
      s1 = __builtin_amdgcn_mfma_f32_32x32x16_f16(k1, qf[cd], s1, 0, 0, 0);
    }

    // in-lane row max (lane holds 32 values of one q-row), tree
    float t8[8];
#pragma unroll
    for (int i = 0; i < 8; ++i)
      t8[i] = fmaxf(fmaxf(s0[i], s0[i + 8]), fmaxf(s1[i], s1[i + 8]));
    float ta = fmaxf(fmaxf(t8[0], t8[1]), fmaxf(t8[2], t8[3]));
    float tb = fmaxf(fmaxf(t8[4], t8[5]), fmaxf(t8[6], t8[7]));
    float tmax = fmaxf(ta, tb);
    tmax = fmaxf(tmax, __shfl_xor(tmax, 32));

    // T13 defer-max: only rescale when max grew past threshold (log2 domain)
    if (!__all(tmax <= m + 8.f)) {
      float mn = fmaxf(m, tmax);
      float fs = __builtin_amdgcn_exp2f(m - mn);
      m = mn;
      l *= fs;
#pragma unroll
      for (int i = 0; i < 16; ++i) { o0[i] *= fs; o1[i] *= fs; }
    }

    // p = 2^(s - m) in place
#pragma unroll
    for (int i = 0; i < 16; ++i) {
      s0[i] = __builtin_amdgcn_exp2f(s0[i] - m);
      s1[i] = __builtin_amdgcn_exp2f(s1[i] - m);
    }
    float a8[8];
#pragma unroll
    for (int i = 0; i < 8; ++i)
      a8[i] = (s0[i] + s0[i + 8]) + (s1[i] + s1[i + 8]);
    float rs = ((a8[0] + a8[1]) + (a8[2] + a8[3])) + ((a8[4] + a8[5]) + (a8[6] + a8[7]));
    rs += __shfl_xor(rs, 32);
    l += rs;

    // pack P^T into PV B-fragments: cvt_pkrtz pairs + permlane32_swap
    f16x8 pf[4];
#define PACKC(src, c, ck)                                                     \
    {                                                                         \
      u32 a0 = pk2(src[8 * (c) + 0], src[8 * (c) + 1]);                       \
      u32 a1 = pk2(src[8 * (c) + 2], src[8 * (c) + 3]);                       \
      u32 b0 = pk2(src[8 * (c) + 4], src[8 * (c) + 5]);                       \
      u32 b1 = pk2(src[8 * (c) + 6], src[8 * (c) + 7]);                       \
      pl32swap(a0, b0);                                                       \
      pl32swap(a1, b1);                                                       \
      u32x4 pw = {a0, a1, b0, b1};                                            \
      pf[ck] = __builtin_bit_cast(f16x8, pw);                                 \
    }
    PACKC(s0, 0, 0);
    PACKC(s0, 1, 1);
    PACKC(s1, 0, 2);
    PACKC(s1, 1, 3);

    // O^T += V^T . P^T : 2 d-halves x 4 kv-chunks
#pragma unroll
    for (int ck = 0; ck < 4; ++ck) {
      const int sl = (((ck << 1) | hi) ^ (l31 & 7)) << 4;
      f16x8 v0 = *(const f16x8*)(Vc + l31 * 128 + sl);
      f16x8 v1 = *(const f16x8*)(Vc + (32 + l31) * 128 + sl);
      o0 = __builtin_amdgcn_mfma_f32_32x32x16_f16(v0, pf[ck], o0, 0, 0, 0);
      o1 = __builtin_amdgcn_mfma_f32_32x32x16_f16(v1, pf[ck], o1, 0, 0, 0);
    }
    __syncthreads();
  }

  // epilogue: lane owns q=myq, d = dm*32 + 8u + 4hi + {0..3}
  float inv = 1.0f / l;
  const int b_ = bh >> 3, h_ = bh & 7;
  f16* orow = Ao + ((size_t)b_ * SEQ + myq) * CDIM + (h_ << 6) + (hi << 2);
#pragma unroll
  for (int u = 0; u < 4; ++u) {
    u32x2 pa = {pk2(o0[4 * u] * inv, o0[4 * u + 1] * inv),
                pk2(o0[4 * u + 2] * inv, o0[4 * u + 3] * inv)};
    *reinterpret_cast<u32x2*>(orow + (u << 3)) = pa;
    u32x2 pb = {pk2(o1[4 * u] * inv, o1[4 * u + 1] * inv),
                pk2(o1[4 * u + 2] * inv, o1[4 * u + 3] * inv)};
    *reinterpret_cast<u32x2*>(orow + 32 + (u << 3)) = pb;
  }
}

extern "C" void kernel_launch(void* const* d_in, const int* in_sizes, int n_in,
                              void* d_out, int out_size, void* d_ws, size_t ws_size,
                              hipStream_t stream) {
  const float* x = (const float*)d_in[0];
  const float* Wqkv = (const float*)d_in[1];
  const float* bqkv = (const float*)d_in[2];
  const float* Wproj = (const float*)d_in[3];
  const float* bproj = (const float*)d_in[4];
  float* out = (float*)d_out;
  char* ws = (char*)d_ws;

  const size_t SZ_X = (size_t)MTOT * CDIM * 2;  // 8 MiB
  f16* xb = (f16*)(ws);
  f16* attno = xb;  // alias: xb dead after QKV GEMM
  f16* wqkvT = (f16*)(ws + SZ_X);
  f16* wprojT = (f16*)(ws + SZ_X + (size_t)1536 * 512 * 2);
  f16* Qwv = (f16*)(ws + SZ_X + (size_t)1536 * 512 * 2 + (size_t)512 * 512 * 2);
  f16* Kwv = (f16*)((char*)Qwv + SZ_X);
  f16* Vwv = (f16*)((char*)Kwv + SZ_X);

  cvt_f32_f16<<<(MTOT * CDIM / 4 + 255) / 256, 256, 0, stream>>>(x, xb, MTOT * CDIM);
  cvt_transpose<<<(512 * 1536 + 255) / 256, 256, 0, stream>>>(Wqkv, wqkvT, 512, 1536);
  cvt_transpose<<<(512 * 512 + 255) / 256, 256, 0, stream>>>(Wproj, wprojT, 512, 512);
  gemm_f16<0><<<64 * 12, 256, 0, stream>>>(xb, wqkvT, bqkv, 1536, Qwv, Kwv, Vwv, nullptr);
  attn_f16<<<16 * 32, 256, 0, stream>>>(Qwv, Kwv, Vwv, attno);
  gemm_f16<1><<<64 * 4, 256, 0, stream>>>(attno, wprojT, bproj, 512, nullptr, nullptr, nullptr, out);
}

// Round 6
// 177.607 us; speedup vs baseline: 1.5949x; 1.0501x over previous
//
#include <hip/hip_runtime.h>
#include <stdint.h>

typedef _Float16 f16;
typedef _Float16 f16x4 __attribute__((ext_vector_type(4)));
typedef _Float16 f16x8 __attribute__((ext_vector_type(8)));
typedef float f32x4 __attribute__((ext_vector_type(4)));
typedef float f32x16 __attribute__((ext_vector_type(16)));
typedef uint32_t u32;
typedef u32 u32x2 __attribute__((ext_vector_type(2)));
typedef u32 u32x4 __attribute__((ext_vector_type(4)));

#define NHEADS 8
#define DH 64
#define BATCH 2
#define SEQ 4096
#define CDIM 512
#define MTOT (BATCH * SEQ)
// softmax scale (1/sqrt(64)) * log2(e), folded into Q at the QKV epilogue
#define QSCALE 0.18033688011112042f

__device__ __forceinline__ void gload_lds16(const void* g, void* l) {
  __builtin_amdgcn_global_load_lds(
      (const __attribute__((address_space(1))) uint32_t*)g,
      (__attribute__((address_space(3))) uint32_t*)l, 16, 0, 0);
}

__device__ __forceinline__ u32 pk2(float a, float b) {
  auto h = __builtin_amdgcn_cvt_pkrtz(a, b);
  return __builtin_bit_cast(u32, h);
}

__device__ __forceinline__ void pl32swap(u32& a, u32& b) {
  asm volatile("v_permlane32_swap_b32 %0, %1" : "+v"(a), "+v"(b));
}

__global__ void cvt_f32_f16(const float* __restrict__ in, f16* __restrict__ outp, int n) {
  int i = (blockIdx.x * 256 + threadIdx.x) * 4;
  if (i < n) {
    float4 v = *(const float4*)(in + i);
    f16x4 o = {(f16)v.x, (f16)v.y, (f16)v.z, (f16)v.w};
    *(f16x4*)(outp + i) = o;
  }
}

__global__ void cvt_transpose(const float* __restrict__ src, f16* __restrict__ dst, int Kd, int Nd) {
  int i = blockIdx.x * 256 + threadIdx.x;
  if (i < Kd * Nd) {
    int k = i / Nd, n = i - k * Nd;
    dst[(size_t)n * Kd + k] = (f16)src[i];
  }
}

// C = A[M,512] * Bt[N,512]^T ; tiles 128x128, BK=64, 4 waves (2x2), 16x16x32 MFMA
template <int MODE>
__global__ __launch_bounds__(256) void gemm_f16(
    const f16* __restrict__ A, const f16* __restrict__ Bt,
    const float* __restrict__ bias, int Ncols,
    f16* __restrict__ Qo, f16* __restrict__ Ko, f16* __restrict__ Vo,
    float* __restrict__ Fo) {
  const int K = CDIM;
  const int nTN = Ncols >> 7;
  const int bm = blockIdx.x / nTN, bn = blockIdx.x % nTN;
  const int M0 = bm << 7, N0 = bn << 7;
  __shared__ __align__(16) char ldsA[128 * 64 * 2];
  __shared__ __align__(16) char ldsB[128 * 64 * 2];
  const int t = threadIdx.x;
  const int w = t >> 6, lane = t & 63;
  const int wr = w >> 1, wc = w & 1;
  const int lm = lane & 15, lk = lane >> 4;
  f32x4 acc[4][4] = {};

  const int srow = t >> 3;
  const int sj = t & 7;

  for (int k0 = 0; k0 < K; k0 += 64) {
    __syncthreads();
#pragma unroll
    for (int q = 0; q < 4; ++q) {
      int row = (q << 5) + srow;
      int col = (sj ^ (row & 7)) << 3;
      gload_lds16(A + (size_t)(M0 + row) * K + k0 + col,
                  ldsA + ((q << 8) + (w << 6)) * 16);
      gload_lds16(Bt + (size_t)(N0 + row) * K + k0 + col,
                  ldsB + ((q << 8) + (w << 6)) * 16);
    }
    asm volatile("s_waitcnt vmcnt(0)" ::: "memory");
    __syncthreads();
#pragma unroll
    for (int h = 0; h < 2; ++h) {
      f16x8 af[4], bf[4];
#pragma unroll
      for (int mi = 0; mi < 4; ++mi) {
        int row = (wr << 6) + (mi << 4) + lm;
        int slot = ((h << 2) + lk) ^ (row & 7);
        af[mi] = *(const f16x8*)(ldsA + row * 128 + slot * 16);
      }
#pragma unroll
      for (int ni = 0; ni < 4; ++ni) {
        int row = (wc << 6) + (ni << 4) + lm;
        int slot = ((h << 2) + lk) ^ (row & 7);
        bf[ni] = *(const f16x8*)(ldsB + row * 128 + slot * 16);
      }
#pragma unroll
      for (int mi = 0; mi < 4; ++mi)
#pragma unroll
        for (int ni = 0; ni < 4; ++ni)
          acc[mi][ni] = __builtin_amdgcn_mfma_f32_16x16x32_f16(af[mi], bf[ni], acc[mi][ni], 0, 0, 0);
    }
  }

  const int cbase = N0 + (wc << 6);
  if (MODE == 0) {
    const int tsec = cbase >> 9;
    const int hh = (cbase & 511) >> 6;
#pragma unroll
    for (int mi = 0; mi < 4; ++mi)
#pragma unroll
      for (int ni = 0; ni < 4; ++ni) {
        int c = cbase + (ni << 4) + lm;
        int d = c & 63;
        float bv = bias[c];
#pragma unroll
        for (int r = 0; r < 4; ++r) {
          int m = M0 + (wr << 6) + (mi << 4) + (lk << 2) + r;
          float v = acc[mi][ni][r] + bv;
          int bb = m >> 12, tok = m & 4095;
          size_t bh = (size_t)bb * NHEADS + hh;
          if (tsec == 0)      Qo[(bh * SEQ + tok) * DH + d] = (f16)(v * QSCALE);
          else if (tsec == 1) Ko[(bh * SEQ + tok) * DH + d] = (f16)v;
          else                Vo[(bh * DH + d) * SEQ + tok] = (f16)v;
        }
      }
  } else {
#pragma unroll
    for (int mi = 0; mi < 4; ++mi)
#pragma unroll
      for (int ni = 0; ni < 4; ++ni) {
        int c = cbase + (ni << 4) + lm;
        float bv = bias[c];
#pragma unroll
        for (int r = 0; r < 4; ++r) {
          int m = M0 + (wr << 6) + (mi << 4) + (lk << 2) + r;
          Fo[(size_t)m * CDIM + c] = acc[mi][ni][r] + bv;
        }
      }
  }
}

// Flash attention, swapped-QK^T 32x32 structure.
// grid = 16 bh x 32 q-tiles(128); block = 4 waves; wave owns 32 q-rows.
// S^T = mfma(K, Q) so each lane holds a full 32-element P-row slice for one q.
// PV computed as O^T = mfma(V^T, P^T); P repacked in-register via cvt_pkrtz +
// v_permlane32_swap (distinct-value operands only — proven in R3).
// Cross-half reduces use __shfl_xor(.,32): the same-value permlane helper
// (R4/R5) produced 1.5e-3 absmax errors and is reverted pending isolation.
// launch_bounds(256,2): grid-limited to 2 blocks/CU -> full register budget.
__global__ __launch_bounds__(256, 2) void attn_f16(
    const f16* __restrict__ Qw, const f16* __restrict__ Kw,
    const f16* __restrict__ Vw, f16* __restrict__ Ao) {
  const int bh = blockIdx.x >> 5;
  const int qt = blockIdx.x & 31;
  const int t = threadIdx.x, lane = t & 63;
  const int l31 = lane & 31, hi = lane >> 5;
  const int w = t >> 6;
  __shared__ __align__(16) char ldsK[2][64 * 128];
  __shared__ __align__(16) char ldsV[2][64 * 128];
  const int q0 = (qt << 7) + (w << 5);
  const int myq = q0 + l31;
  const f16* Qb = Qw + ((size_t)bh * SEQ + myq) * DH;
  f16x8 qf[4];
#pragma unroll
  for (int cd = 0; cd < 4; ++cd)
    qf[cd] = *(const f16x8*)(Qb + cd * 16 + hi * 8);
  f32x16 o0 = {}, o1 = {};
  float m = -1e30f, l = 0.f;
  const f16* Kb = Kw + (size_t)bh * SEQ * DH;
  const f16* Vb = Vw + (size_t)bh * DH * SEQ;
  const int srow = t >> 3, sj = t & 7;

#define STAGE(buf, kv0_)                                                      \
  {                                                                           \
    _Pragma("unroll") for (int q2 = 0; q2 < 2; ++q2) {                        \
      const int row = (q2 << 5) + srow;                                       \
      const int col = (sj ^ (row & 7)) << 3;                                  \
      gload_lds16(Kb + (size_t)((kv0_) + row) * DH + col,                     \
                  ldsK[buf] + (q2 << 12) + srow * 128 + sj * 16);             \
      gload_lds16(Vb + (size_t)row * SEQ + (kv0_) + col,                      \
                  ldsV[buf] + (q2 << 12) + srow * 128 + sj * 16);             \
    }                                                                         \
  }

  STAGE(0, 0);
  __syncthreads();

#pragma unroll 1
  for (int tt = 0; tt < 64; ++tt) {
    const int cur = tt & 1;
    const char* Kc = ldsK[cur];
    const char* Vc = ldsV[cur];
    if (tt < 63) STAGE(cur ^ 1, (tt + 1) << 6);

    // S^T[kv][q]: 2 kv-halves x 4 d-chunks
    f32x16 s0 = {}, s1 = {};
#pragma unroll
    for (int cd = 0; cd < 4; ++cd) {
      const int sl = (((cd << 1) | hi) ^ (l31 & 7)) << 4;
      f16x8 k0 = *(const f16x8*)(Kc + l31 * 128 + sl);
      f16x8 k1 = *(const f16x8*)(Kc + (32 + l31) * 128 + sl);
      s0 = __builtin_amdgcn_mfma_f32_32x32x16_f16(k0, qf[cd], s0, 0, 0, 0);
      s1 = __builtin_amdgcn_mfma_f32_32x32x16_f16(k1, qf[cd], s1, 0, 0, 0);
    }

    // in-lane row max (nested fmaxf -> v_max3 fusion), shfl cross-half
    float v8[8];
#pragma unroll
    for (int i = 0; i < 8; ++i)
      v8[i] = fmaxf(fmaxf(s0[i], s0[i + 8]), fmaxf(s1[i], s1[i + 8]));
    float ta = fmaxf(fmaxf(v8[0], v8[1]), fmaxf(v8[2], v8[3]));
    float tb = fmaxf(fmaxf(v8[4], v8[5]), fmaxf(v8[6], v8[7]));
    float tmax = fmaxf(ta, tb);
    tmax = fmaxf(tmax, __shfl_xor(tmax, 32));

    // T13 defer-max: only rescale when max grew past threshold (log2 domain)
    if (!__all(tmax <= m + 8.f)) {
      float mn = fmaxf(m, tmax);
      float fs = __builtin_amdgcn_exp2f(m - mn);
      m = mn;
      l *= fs;
#pragma unroll
      for (int i = 0; i < 16; ++i) { o0[i] *= fs; o1[i] *= fs; }
    }

    // p = 2^(s - m) in place
#pragma unroll
    for (int i = 0; i < 16; ++i) {
      s0[i] = __builtin_amdgcn_exp2f(s0[i] - m);
      s1[i] = __builtin_amdgcn_exp2f(s1[i] - m);
    }

    // row-sum: f32 add tree + shfl cross-half
    float a8[8];
#pragma unroll
    for (int i = 0; i < 8; ++i)
      a8[i] = (s0[i] + s0[i + 8]) + (s1[i] + s1[i + 8]);
    float rs = ((a8[0] + a8[1]) + (a8[2] + a8[3])) + ((a8[4] + a8[5]) + (a8[6] + a8[7]));
    rs += __shfl_xor(rs, 32);
    l += rs;

    // pack P^T into PV B-fragments: cvt_pkrtz pairs + permlane32_swap
    f16x8 pf[4];
#define PACKC(src, c, ck)                                                     \
    {                                                                         \
      u32 a0 = pk2(src[8 * (c) + 0], src[8 * (c) + 1]);                       \
      u32 a1 = pk2(src[8 * (c) + 2], src[8 * (c) + 3]);                       \
      u32 b0 = pk2(src[8 * (c) + 4], src[8 * (c) + 5]);                       \
      u32 b1 = pk2(src[8 * (c) + 6], src[8 * (c) + 7]);                       \
      pl32swap(a0, b0);                                                       \
      pl32swap(a1, b1);                                                       \
      u32x4 pw = {a0, a1, b0, b1};                                            \
      pf[ck] = __builtin_bit_cast(f16x8, pw);                                 \
    }
    PACKC(s0, 0, 0);
    PACKC(s0, 1, 1);
    PACKC(s1, 0, 2);
    PACKC(s1, 1, 3);

    // O^T += V^T . P^T : 2 d-halves x 4 kv-chunks
#pragma unroll
    for (int ck = 0; ck < 4; ++ck) {
      const int sl = (((ck << 1) | hi) ^ (l31 & 7)) << 4;
      f16x8 v0 = *(const f16x8*)(Vc + l31 * 128 + sl);
      f16x8 v1 = *(const f16x8*)(Vc + (32 + l31) * 128 + sl);
      o0 = __builtin_amdgcn_mfma_f32_32x32x16_f16(v0, pf[ck], o0, 0, 0, 0);
      o1 = __builtin_amdgcn_mfma_f32_32x32x16_f16(v1, pf[ck], o1, 0, 0, 0);
    }
    __syncthreads();
  }

  // epilogue: lane owns q=myq, d = dm*32 + 8u + 4hi + {0..3}
  float inv = 1.0f / l;
  const int b_ = bh >> 3, h_ = bh & 7;
  f16* orow = Ao + ((size_t)b_ * SEQ + myq) * CDIM + (h_ << 6) + (hi << 2);
#pragma unroll
  for (int u = 0; u < 4; ++u) {
    u32x2 pa = {pk2(o0[4 * u] * inv, o0[4 * u + 1] * inv),
                pk2(o0[4 * u + 2] * inv, o0[4 * u + 3] * inv)};
    *reinterpret_cast<u32x2*>(orow + (u << 3)) = pa;
    u32x2 pb = {pk2(o1[4 * u] * inv, o1[4 * u + 1] * inv),
                pk2(o1[4 * u + 2] * inv, o1[4 * u + 3] * inv)};
    *reinterpret_cast<u32x2*>(orow + 32 + (u << 3)) = pb;
  }
}

extern "C" void kernel_launch(void* const* d_in, const int* in_sizes, int n_in,
                              void* d_out, int out_size, void* d_ws, size_t ws_size,
                              hipStream_t stream) {
  const float* x = (const float*)d_in[0];
  const float* Wqkv = (const float*)d_in[1];
  const float* bqkv = (const float*)d_in[2];
  const float* Wproj = (const float*)d_in[3];
  const float* bproj = (const float*)d_in[4];
  float* out = (float*)d_out;
  char* ws = (char*)d_ws;

  const size_t SZ_X = (size_t)MTOT * CDIM * 2;  // 8 MiB
  f16* xb = (f16*)(ws);
  f16* attno = xb;  // alias: xb dead after QKV GEMM
  f16* wqkvT = (f16*)(ws + SZ_X);
  f16* wprojT = (f16*)(ws + SZ_X + (size_t)1536 * 512 * 2);
  f16* Qwv = (f16*)(ws + SZ_X + (size_t)1536 * 512 * 2 + (size_t)512 * 512 * 2);
  f16* Kwv = (f16*)((char*)Qwv + SZ_X);
  f16* Vwv = (f16*)((char*)Kwv + SZ_X);

  cvt_f32_f16<<<(MTOT * CDIM / 4 + 255) / 256, 256, 0, stream>>>(x, xb, MTOT * CDIM);
  cvt_transpose<<<(512 * 1536 + 255) / 256, 256, 0, stream>>>(Wqkv, wqkvT, 512, 1536);
  cvt_transpose<<<(512 * 512 + 255) / 256, 256, 0, stream>>>(Wproj, wprojT, 512, 512);
  gemm_f16<0><<<64 * 12, 256, 0, stream>>>(xb, wqkvT, bqkv, 1536, Qwv, Kwv, Vwv, nullptr);
  attn_f16<<<16 * 32, 256, 0, stream>>>(Qwv, Kwv, Vwv, attno);
  gemm_f16<1><<<64 * 4, 256, 0, stream>>>(attno, wprojT, bproj, 512, nullptr, nullptr, nullptr, out);
}